// Round 12
// baseline (2015.289 us; speedup 1.0000x reference)
//
#include <hip/hip_runtime.h>
#include <math.h>

#define N_PTS 4096
#define BATCH 4
#define KNN 10

__device__ __forceinline__ unsigned f2key(float x) {
    unsigned u = __float_as_uint(x);
    return (u & 0x80000000u) ? ~u : (u | 0x80000000u);
}
__device__ __forceinline__ float key2f(unsigned k) {
    unsigned u = (k & 0x80000000u) ? (k & 0x7FFFFFFFu) : ~k;
    return __uint_as_float(u);
}

__device__ __forceinline__ float lrelu(float h) { return (h > 0.f) ? h : 0.2f * h; }

// packed sort key: larger == better; ties on value -> smaller index wins
__device__ __forceinline__ unsigned long long pack_kd(float v, int c) {
    return ((unsigned long long)f2key(v) << 32) | (unsigned)~(unsigned)c;
}

// broadcast 64-bit value from a wave-uniform source lane via readlane
__device__ __forceinline__ unsigned long long bcast64(unsigned long long x, int src) {
    unsigned lo = (unsigned)__builtin_amdgcn_readlane((int)(unsigned)(x & 0xFFFFFFFFu), src);
    unsigned hi = (unsigned)__builtin_amdgcn_readlane((int)(unsigned)(x >> 32), src);
    return ((unsigned long long)hi << 32) | lo;
}

// ---------------- squared norms ----------------
__global__ void sq_kernel(const float* __restrict__ x, int xstr, int D,
                          float* __restrict__ sq) {
    int g = blockIdx.x * blockDim.x + threadIdx.x;
    if (g >= BATCH * N_PTS) return;
    const float* row = x + (long)g * xstr;
    float s = 0.f;
    if ((D & 3) == 0) {
        for (int c = 0; c < D; c += 4) {
            float4 v = *(const float4*)&row[c];
            s += v.x * v.x + v.y * v.y + v.z * v.z + v.w * v.w;
        }
    } else {
        for (int c = 0; c < D; ++c) { float v = row[c]; s += v * v; }
    }
    sq[g] = s;
}

// ---------------- layer-1 knn (D=3): on-the-fly dist + wave top-11 --------
__global__ __launch_bounds__(256) void knn3_kernel(const float* __restrict__ x,
                                                   const float* __restrict__ sq,
                                                   int* __restrict__ idxout) {
    int b = blockIdx.y;
    int wave = threadIdx.x >> 6;
    int lane = threadIdx.x & 63;
    int row = blockIdx.x * 4 + wave;
    const float* xb = x + (long)b * N_PTS * 3;
    const float* sqb = sq + b * N_PTS;
    float x0 = xb[row * 3 + 0], x1 = xb[row * 3 + 1], x2 = xb[row * 3 + 2];
    float sr = sqb[row];

    unsigned long long elem = 0ull, T = 0ull;
    float Tf = -INFINITY;

    int c = lane;
    float y0 = xb[c * 3 + 0], y1 = xb[c * 3 + 1], y2 = xb[c * 3 + 2];
    float sc = sqb[c];
    for (int it = 0; it < 64; ++it) {
        float ny0, ny1, ny2, nsc;
        int nc = c + 64;
        if (it < 63) {
            ny0 = xb[nc * 3 + 0]; ny1 = xb[nc * 3 + 1]; ny2 = xb[nc * 3 + 2];
            nsc = sqb[nc];
        }
        float s = 0.f;
        s += x0 * y0; s += x1 * y1; s += x2 * y2;
        float d = 2.f * s - sr - sc;
        if (__ballot(d >= Tf)) {
            unsigned long long kq = pack_kd(d, c);
            unsigned long long mask;
            while ((mask = __ballot(kq > T)) != 0ull) {
                int src = __ffsll(mask) - 1;
                unsigned long long kb = bcast64(kq, src);
                if (lane == src) kq = 0ull;
                unsigned long long below = __ballot(elem > kb);
                int pos = __popcll(below);
                unsigned long long prev = __shfl_up(elem, 1);
                if (lane == pos) elem = kb;
                else if (lane > pos && lane <= 10) elem = prev;
                T = bcast64(elem, 10);
                Tf = key2f((unsigned)(T >> 32));
            }
        }
        y0 = ny0; y1 = ny1; y2 = ny2; sc = nsc; c = nc;
    }
    if (lane >= 1 && lane <= 10) {
        idxout[((long)b * N_PTS + row) * KNN + (lane - 1)] =
            (int)~(unsigned)(elem & 0xFFFFFFFFull);
    }
}

// ---------------- neg-distance tile GEMM (slab fallback, round-1 exact) ----
__global__ __launch_bounds__(256) void dist_kernel(const float* __restrict__ x,
                                                   const float* __restrict__ sq,
                                                   float* __restrict__ dist,
                                                   int xstr, int D, int row0) {
    __shared__ float As[16][132];
    __shared__ float Bs[16][132];
    int b = blockIdx.z;
    const float* xb = x + (long)b * N_PTS * xstr;
    const float* sqb = sq + b * N_PTS;
    float* db = dist + (long)b * 1024 * N_PTS;
    int r0 = row0 + blockIdx.y * 128;
    int c0 = blockIdx.x * 128;
    int tx = threadIdx.x & 15, ty = threadIdx.x >> 4;
    float acc[8][8] = {};
    int nk = (D + 15) >> 4;
    for (int kt = 0; kt < nk; ++kt) {
        int k0 = kt * 16;
        for (int e = threadIdx.x; e < 2048; e += 256) {
            int kk = e & 15, r = e >> 4;
            int c = k0 + kk;
            As[kk][r] = (c < D) ? xb[(long)(r0 + r) * xstr + c] : 0.f;
            Bs[kk][r] = (c < D) ? xb[(long)(c0 + r) * xstr + c] : 0.f;
        }
        __syncthreads();
        #pragma unroll
        for (int kk = 0; kk < 16; ++kk) {
            float a[8], bb[8];
            *(float4*)&a[0] = *(float4*)&As[kk][ty * 8];
            *(float4*)&a[4] = *(float4*)&As[kk][ty * 8 + 4];
            *(float4*)&bb[0] = *(float4*)&Bs[kk][tx * 8];
            *(float4*)&bb[4] = *(float4*)&Bs[kk][tx * 8 + 4];
            #pragma unroll
            for (int i = 0; i < 8; ++i)
                #pragma unroll
                for (int j = 0; j < 8; ++j) acc[i][j] += a[i] * bb[j];
        }
        __syncthreads();
    }
    #pragma unroll
    for (int i = 0; i < 8; ++i) {
        int lr = blockIdx.y * 128 + ty * 8 + i;
        float sr = sqb[r0 + ty * 8 + i];
        int cb = c0 + tx * 8;
        float4 v0, v1;
        v0.x = 2.f * acc[i][0] - sr - sqb[cb + 0];
        v0.y = 2.f * acc[i][1] - sr - sqb[cb + 1];
        v0.z = 2.f * acc[i][2] - sr - sqb[cb + 2];
        v0.w = 2.f * acc[i][3] - sr - sqb[cb + 3];
        v1.x = 2.f * acc[i][4] - sr - sqb[cb + 4];
        v1.y = 2.f * acc[i][5] - sr - sqb[cb + 5];
        v1.z = 2.f * acc[i][6] - sr - sqb[cb + 6];
        v1.w = 2.f * acc[i][7] - sr - sqb[cb + 7];
        *(float4*)&db[(long)lr * N_PTS + cb] = v0;
        *(float4*)&db[(long)lr * N_PTS + cb + 4] = v1;
    }
}

// ---------------- symmetric full-matrix dist + per-tile row maxima --------
__global__ __launch_bounds__(256) void distsym_kernel(const float* __restrict__ x,
                                                      const float* __restrict__ sq,
                                                      float* __restrict__ dist,
                                                      float* __restrict__ maxbuf,
                                                      int xstr, int D) {
    __shared__ float As[16][132];
    __shared__ float Bs[16][132];
    __shared__ float Tt[64][132];
    int b = blockIdx.z;
    int t = blockIdx.x, br = 0;
    while (t >= 32 - br) { t -= 32 - br; ++br; }
    int bc = br + t;
    const float* xb = x + (long)b * N_PTS * xstr;
    const float* sqb = sq + b * N_PTS;
    float* db = dist + (long)b * N_PTS * N_PTS;
    int r0 = br * 128, c0 = bc * 128;
    int tx = threadIdx.x & 15, ty = threadIdx.x >> 4;
    float acc[8][8] = {};
    int nk = (D + 15) >> 4;
    for (int kt = 0; kt < nk; ++kt) {
        int k0 = kt * 16;
        for (int e = threadIdx.x; e < 2048; e += 256) {
            int kk = e & 15, r = e >> 4;
            int c = k0 + kk;
            As[kk][r] = (c < D) ? xb[(long)(r0 + r) * xstr + c] : 0.f;
            Bs[kk][r] = (c < D) ? xb[(long)(c0 + r) * xstr + c] : 0.f;
        }
        __syncthreads();
        #pragma unroll
        for (int kk = 0; kk < 16; ++kk) {
            float a[8], bb[8];
            *(float4*)&a[0] = *(float4*)&As[kk][ty * 8];
            *(float4*)&a[4] = *(float4*)&As[kk][ty * 8 + 4];
            *(float4*)&bb[0] = *(float4*)&Bs[kk][tx * 8];
            *(float4*)&bb[4] = *(float4*)&Bs[kk][tx * 8 + 4];
            #pragma unroll
            for (int i = 0; i < 8; ++i)
                #pragma unroll
                for (int j = 0; j < 8; ++j) acc[i][j] += a[i] * bb[j];
        }
        __syncthreads();
    }
    float sqr[8], sqc[8];
    #pragma unroll
    for (int i = 0; i < 8; ++i) sqr[i] = sqb[r0 + ty * 8 + i];
    #pragma unroll
    for (int j = 0; j < 8; ++j) sqc[j] = sqb[c0 + tx * 8 + j];
    #pragma unroll
    for (int i = 0; i < 8; ++i) {
        int R = r0 + ty * 8 + i;
        int cb = c0 + tx * 8;
        float4 v0, v1;
        v0.x = 2.f * acc[i][0] - sqr[i] - sqc[0];
        v0.y = 2.f * acc[i][1] - sqr[i] - sqc[1];
        v0.z = 2.f * acc[i][2] - sqr[i] - sqc[2];
        v0.w = 2.f * acc[i][3] - sqr[i] - sqc[3];
        v1.x = 2.f * acc[i][4] - sqr[i] - sqc[4];
        v1.y = 2.f * acc[i][5] - sqr[i] - sqc[5];
        v1.z = 2.f * acc[i][6] - sqr[i] - sqc[6];
        v1.w = 2.f * acc[i][7] - sqr[i] - sqc[7];
        *(float4*)&db[(long)R * N_PTS + cb] = v0;
        *(float4*)&db[(long)R * N_PTS + cb + 4] = v1;
        // row max over this tile (16 tx lanes are consecutive in the wave)
        float tm = fmaxf(fmaxf(fmaxf(v0.x, v0.y), fmaxf(v0.z, v0.w)),
                         fmaxf(fmaxf(v1.x, v1.y), fmaxf(v1.z, v1.w)));
        #pragma unroll
        for (int off = 1; off < 16; off <<= 1)
            tm = fmaxf(tm, __shfl_xor(tm, off, 16));
        if (tx == 0) maxbuf[((long)b * N_PTS + R) * 32 + bc] = tm;
    }
    if (br == bc) return;
    #pragma unroll
    for (int h = 0; h < 2; ++h) {
        __syncthreads();
        if ((tx >> 3) == h) {
            int txl = tx & 7;
            #pragma unroll
            for (int j = 0; j < 8; ++j)
                #pragma unroll
                for (int i = 0; i < 8; ++i)
                    Tt[txl * 8 + j][ty * 8 + i] =
                        (2.f * acc[i][j] - sqc[j]) - sqr[i];
        }
        __syncthreads();
        for (int e = threadIdx.x; e < 2048; e += 256) {
            int rr = e >> 5, cc = (e & 31) << 2;
            *(float4*)&db[(long)(c0 + h * 64 + rr) * N_PTS + r0 + cc] =
                *(const float4*)&Tt[rr][cc];
        }
        // mirrored row maxima from Tt — float4-vectorized (8 b128 reads/thread)
        {
            int rr = threadIdx.x >> 2, q = threadIdx.x & 3;
            float tm = -INFINITY;
            #pragma unroll
            for (int cc = 0; cc < 8; ++cc) {
                float4 v = *(const float4*)&Tt[rr][q * 32 + cc * 4];
                tm = fmaxf(tm, fmaxf(fmaxf(v.x, v.y), fmaxf(v.z, v.w)));
            }
            tm = fmaxf(tm, __shfl_xor(tm, 1, 4));
            tm = fmaxf(tm, __shfl_xor(tm, 2, 4));
            if (q == 0)
                maxbuf[((long)b * N_PTS + c0 + h * 64 + rr) * 32 + br] = tm;
        }
    }
}

// ---------------- wave-collective top-(k+1) (slab fallback) ------
__global__ __launch_bounds__(256) void topk_kernel(const float* __restrict__ dist,
                                                   int* __restrict__ idxout, int row0) {
    int b = blockIdx.y;
    int wave = threadIdx.x >> 6;
    int lane = threadIdx.x & 63;
    int row_local = blockIdx.x * 4 + wave;
    const float4* d4 =
        (const float4*)(dist + (long)b * 1024 * N_PTS + (long)row_local * N_PTS);

    unsigned long long elem = 0ull;
    unsigned long long T = 0ull;
    float Tf = -INFINITY;

    float4 cur = d4[lane];
    for (int jj = 0; jj < 16; ++jj) {
        float4 nxt;
        if (jj < 15) nxt = d4[(jj + 1) * 64 + lane];
        float vmax = fmaxf(fmaxf(cur.x, cur.y), fmaxf(cur.z, cur.w));
        if (__ballot(vmax >= Tf)) {
            int cbase = jj * 256 + lane * 4;
            unsigned long long kc[4];
            kc[0] = pack_kd(cur.x, cbase + 0);
            kc[1] = pack_kd(cur.y, cbase + 1);
            kc[2] = pack_kd(cur.z, cbase + 2);
            kc[3] = pack_kd(cur.w, cbase + 3);
            #pragma unroll
            for (int q = 0; q < 4; ++q) {
                unsigned long long kq = kc[q];
                unsigned long long mask;
                while ((mask = __ballot(kq > T)) != 0ull) {
                    int src = __ffsll(mask) - 1;
                    unsigned long long kb = bcast64(kq, src);
                    if (lane == src) kq = 0ull;
                    unsigned long long below = __ballot(elem > kb);
                    int pos = __popcll(below);
                    unsigned long long prev = __shfl_up(elem, 1);
                    if (lane == pos) elem = kb;
                    else if (lane > pos && lane <= 10) elem = prev;
                    T = bcast64(elem, 10);
                    Tf = key2f((unsigned)(T >> 32));
                }
            }
        }
        cur = nxt;
    }
    if (lane >= 1 && lane <= 10) {
        int c = (int)~(unsigned)(elem & 0xFFFFFFFFu);
        idxout[((long)b * N_PTS + row0 + row_local) * KNN + (lane - 1)] = c;
    }
}

// ---------------- max-skip topk: process tiles in descending-max order ----
__global__ __launch_bounds__(256) void topkms_kernel(const float* __restrict__ dist,
                                                     const float* __restrict__ maxbuf,
                                                     int* __restrict__ idxout) {
    int b = blockIdx.y;
    int wave = threadIdx.x >> 6;
    int lane = threadIdx.x & 63;
    int row = blockIdx.x * 4 + wave;
    const float* drow = dist + (long)b * N_PTS * N_PTS + (long)row * N_PTS;
    float mx = (lane < 32) ? maxbuf[((long)b * N_PTS + row) * 32 + lane] : -INFINITY;

    unsigned long long elem = 0ull, T = 0ull;
    float Tf = -INFINITY;

    while (1) {
        // wave argmax over remaining tile maxima
        float bv = mx; int bi = lane;
        #pragma unroll
        for (int off = 32; off > 0; off >>= 1) {
            float ov = __shfl_xor(bv, off);
            int oi = __shfl_xor(bi, off);
            if (ov > bv || (ov == bv && oi < bi)) { bv = ov; bi = oi; }
        }
        if (!(bv >= Tf)) break;  // all remaining tiles lose to rank-10
        // process tile bi: 128 cols, 2 per lane
        int cb = bi * 128 + lane * 2;
        float2 v = *(const float2*)&drow[cb];
        unsigned long long kc[2];
        kc[0] = pack_kd(v.x, cb);
        kc[1] = pack_kd(v.y, cb + 1);
        #pragma unroll
        for (int q = 0; q < 2; ++q) {
            unsigned long long kq = kc[q];
            unsigned long long mask;
            while ((mask = __ballot(kq > T)) != 0ull) {
                int src = __ffsll(mask) - 1;
                unsigned long long kb = bcast64(kq, src);
                if (lane == src) kq = 0ull;
                unsigned long long below = __ballot(elem > kb);
                int pos = __popcll(below);
                unsigned long long prev = __shfl_up(elem, 1);
                if (lane == pos) elem = kb;
                else if (lane > pos && lane <= 10) elem = prev;
                T = bcast64(elem, 10);
                Tf = key2f((unsigned)(T >> 32));
            }
        }
        if (lane == bi) mx = -INFINITY;  // mark processed
    }
    if (lane >= 1 && lane <= 10) {
        int c = (int)~(unsigned)(elem & 0xFFFFFFFFu);
        idxout[((long)b * N_PTS + row) * KNN + (lane - 1)] = c;
    }
}

// ---------------- edge conv L1 (DIN=3, fused path) ----------------
template <int DIN, int DOUT, int PTS, int TPP>
__global__ __launch_bounds__(256) void edgeconv_kernel(
    const float* __restrict__ x, int xstr, const int* __restrict__ idx,
    const float* __restrict__ w, const float* __restrict__ gamma,
    const float* __restrict__ beta, float* __restrict__ out, int outoff) {
    constexpr int DP = DIN + 1;
    constexpr int C2 = 2 * DIN;
    __shared__ float ctr[PTS][DP];
    __shared__ float nm[PTS][KNN][DP];
    int p0 = blockIdx.x * PTS;
    for (int e = threadIdx.x; e < PTS * DIN; e += 256) {
        int p = e / DIN, c = e - p * DIN;
        ctr[p][c] = x[(long)(p0 + p) * xstr + c];
    }
    __syncthreads();
    for (int e = threadIdx.x; e < PTS * KNN * DIN; e += 256) {
        int p = e / (KNN * DIN);
        int rem = e - p * (KNN * DIN);
        int kk = rem / DIN, c = rem - kk * DIN;
        int g = p0 + p;
        int nb = (g & ~(N_PTS - 1)) + idx[(long)g * KNN + kk];
        nm[p][kk][c] = x[(long)nb * xstr + c] - ctr[p][c];
    }
    __syncthreads();
    int p = threadIdx.x / TPP;
    int og = (threadIdx.x % TPP) * 4;
    float gs[4], bt[4];
    #pragma unroll
    for (int j = 0; j < 4; ++j) {
        gs[j] = gamma[og + j] / sqrtf(1.f + 1e-5f);
        bt[j] = beta[og + j];
    }
    float base[4] = {0.f, 0.f, 0.f, 0.f};
    for (int c = 0; c < DIN; ++c) {
        float cv = ctr[p][c];
        #pragma unroll
        for (int j = 0; j < 4; ++j) base[j] += cv * w[(og + j) * C2 + DIN + c];
    }
    float acc[KNN][4];
    #pragma unroll
    for (int kk = 0; kk < KNN; ++kk)
        #pragma unroll
        for (int j = 0; j < 4; ++j) acc[kk][j] = base[j];
    for (int c = 0; c < DIN; ++c) {
        float w4[4];
        #pragma unroll
        for (int j = 0; j < 4; ++j) w4[j] = w[(og + j) * C2 + c];
        #pragma unroll
        for (int kk = 0; kk < KNN; ++kk) {
            float nv = nm[p][kk][c];
            #pragma unroll
            for (int j = 0; j < 4; ++j) acc[kk][j] += nv * w4[j];
        }
    }
    float best[4] = {-INFINITY, -INFINITY, -INFINITY, -INFINITY};
    #pragma unroll
    for (int kk = 0; kk < KNN; ++kk)
        #pragma unroll
        for (int j = 0; j < 4; ++j)
            best[j] = fmaxf(best[j], lrelu(acc[kk][j] * gs[j] + bt[j]));
    #pragma unroll
    for (int j = 0; j < 4; ++j)
        out[(long)(p0 + p) * 512 + outoff + og + j] = best[j];
}

// ---------------- uv GEMM: uv[r][j] = sum_k x[r][k] * Bcat[k][j] ----------
template <int DIN, int DOUT>
__global__ __launch_bounds__(256) void uvgemm_kernel(
    const float* __restrict__ x, int xoff, const float* __restrict__ w,
    float* __restrict__ uv) {
    constexpr int NC = 2 * DOUT;
    __shared__ float As[16][132];
    __shared__ float Bs[16][132];
    int r0 = blockIdx.y * 128;
    int c0 = blockIdx.x * 128;
    int tx = threadIdx.x & 15, ty = threadIdx.x >> 4;
    float acc[8][8] = {};
    #pragma unroll 1
    for (int kt = 0; kt < DIN / 16; ++kt) {
        int k0 = kt * 16;
        for (int e = threadIdx.x; e < 2048; e += 256) {
            int kk = e & 15, r = e >> 4;
            As[kk][r] = x[(long)(r0 + r) * 512 + xoff + k0 + kk];
            int jg = c0 + r;
            Bs[kk][r] = (jg < DOUT) ? w[(long)jg * (2 * DIN) + k0 + kk]
                                    : w[(long)(jg - DOUT) * (2 * DIN) + DIN + k0 + kk];
        }
        __syncthreads();
        #pragma unroll
        for (int kk = 0; kk < 16; ++kk) {
            float a[8], bb[8];
            *(float4*)&a[0] = *(float4*)&As[kk][ty * 8];
            *(float4*)&a[4] = *(float4*)&As[kk][ty * 8 + 4];
            *(float4*)&bb[0] = *(float4*)&Bs[kk][tx * 8];
            *(float4*)&bb[4] = *(float4*)&Bs[kk][tx * 8 + 4];
            #pragma unroll
            for (int i = 0; i < 8; ++i)
                #pragma unroll
                for (int j = 0; j < 8; ++j) acc[i][j] += a[i] * bb[j];
        }
        __syncthreads();
    }
    #pragma unroll
    for (int i = 0; i < 8; ++i) {
        int r = r0 + ty * 8 + i;
        int cb = c0 + tx * 8;
        *(float4*)&uv[(long)r * NC + cb] = *(float4*)&acc[i][0];
        *(float4*)&uv[(long)r * NC + cb + 4] = *(float4*)&acc[i][4];
    }
}

// ---------------- edge max epilogue: h = u[nb] - u[n] + v[n] --------------
template <int DOUT>
__global__ __launch_bounds__(256) void edgemax_kernel(
    const float* __restrict__ uv, const int* __restrict__ idx,
    const float* __restrict__ gamma, const float* __restrict__ beta,
    float* __restrict__ out, int outoff) {
    constexpr int NC = 2 * DOUT;
    constexpr int TPP = DOUT / 4;
    constexpr int TP = 256 / TPP;
    __shared__ int sidx[TP][KNN];
    int p0 = blockIdx.x * TP;
    for (int e = threadIdx.x; e < TP * KNN; e += 256)
        sidx[e / KNN][e % KNN] = idx[(long)(p0 + e / KNN) * KNN + (e % KNN)];
    __syncthreads();
    int p = threadIdx.x / TPP;
    int og = (threadIdx.x % TPP) * 4;
    int g = p0 + p;
    int base_pt = g & ~(N_PTS - 1);
    const float* rowg = uv + (long)g * NC;
    float4 u_n = *(const float4*)&rowg[og];
    float4 v_n = *(const float4*)&rowg[DOUT + og];
    float c0 = v_n.x - u_n.x, c1 = v_n.y - u_n.y;
    float c2 = v_n.z - u_n.z, c3 = v_n.w - u_n.w;
    const float rs = 1.f / sqrtf(1.f + 1e-5f);
    float gs0 = gamma[og + 0] * rs, gs1 = gamma[og + 1] * rs;
    float gs2 = gamma[og + 2] * rs, gs3 = gamma[og + 3] * rs;
    float bt0 = beta[og + 0], bt1 = beta[og + 1];
    float bt2 = beta[og + 2], bt3 = beta[og + 3];
    float b0 = -INFINITY, b1 = -INFINITY, b2 = -INFINITY, b3 = -INFINITY;
    #pragma unroll
    for (int kk = 0; kk < KNN; ++kk) {
        int nb = base_pt + sidx[p][kk];
        float4 ub = *(const float4*)&uv[(long)nb * NC + og];
        b0 = fmaxf(b0, lrelu((ub.x + c0) * gs0 + bt0));
        b1 = fmaxf(b1, lrelu((ub.y + c1) * gs1 + bt1));
        b2 = fmaxf(b2, lrelu((ub.z + c2) * gs2 + bt2));
        b3 = fmaxf(b3, lrelu((ub.w + c3) * gs3 + bt3));
    }
    float4 o4; o4.x = b0; o4.y = b1; o4.z = b2; o4.w = b3;
    *(float4*)&out[(long)g * 512 + outoff + og] = o4;
}

// ---------------- init h5 key buffer ----------------
__global__ void init_h5_kernel(unsigned* __restrict__ h5key) {
    int t = blockIdx.x * blockDim.x + threadIdx.x;
    if (t < BATCH * 1024) h5key[t] = 0u;
}

// ---------------- w5 GEMM + BN + lrelu + max over n, 128x256 tile ---------
// 2x wider tile than before: halves A re-staging and barriers per FLOP.
// Thread covers cols {tx*8+j} and {128+tx*8+j} (two 4-way-aliased read
// groups, same LDS pattern as the proven 8x8 kernel). Per-output fma
// sequence identical to the 128x128 version; n-max reduction is a pure
// fmax tree (exact) => h5key bit-identical.
__global__ __launch_bounds__(256) void w5max_kernel(
    const float* __restrict__ cat, const float* __restrict__ w5,
    const float* __restrict__ g5, const float* __restrict__ b5,
    unsigned* __restrict__ h5key) {
    __shared__ float As[16][132];
    __shared__ float Bs[16][260];
    __shared__ float red[16][256];
    int b = blockIdx.z;
    int n0 = blockIdx.y * 128, o0 = blockIdx.x * 256;
    int tx = threadIdx.x & 15, ty = threadIdx.x >> 4;
    const float* A = cat + (long)b * N_PTS * 512;
    float acc[8][16] = {};
    for (int kt = 0; kt < 32; ++kt) {
        int k0 = kt * 16;
        for (int e = threadIdx.x; e < 2048; e += 256) {
            int kk = e & 15, r = e >> 4;
            As[kk][r] = A[(long)(n0 + r) * 512 + k0 + kk];
        }
        for (int e = threadIdx.x; e < 4096; e += 256) {
            int kk = e & 15, r = e >> 4;
            Bs[kk][r] = w5[(long)(o0 + r) * 512 + k0 + kk];
        }
        __syncthreads();
        #pragma unroll
        for (int kk = 0; kk < 16; ++kk) {
            float a[8], bb[16];
            *(float4*)&a[0] = *(float4*)&As[kk][ty * 8];
            *(float4*)&a[4] = *(float4*)&As[kk][ty * 8 + 4];
            *(float4*)&bb[0] = *(float4*)&Bs[kk][tx * 8];
            *(float4*)&bb[4] = *(float4*)&Bs[kk][tx * 8 + 4];
            *(float4*)&bb[8] = *(float4*)&Bs[kk][128 + tx * 8];
            *(float4*)&bb[12] = *(float4*)&Bs[kk][128 + tx * 8 + 4];
            #pragma unroll
            for (int i = 0; i < 8; ++i)
                #pragma unroll
                for (int j = 0; j < 16; ++j) acc[i][j] += a[i] * bb[j];
        }
        __syncthreads();
    }
    // per-thread col maxima; col(j) = tx*8+j (j<8) or 128+tx*8+(j-8)
    #pragma unroll
    for (int j = 0; j < 16; ++j) {
        int col = (j < 8) ? (tx * 8 + j) : (128 + tx * 8 + (j - 8));
        int o = o0 + col;
        float gsc = g5[o] / sqrtf(1.f + 1e-5f);
        float bto = b5[o];
        float m = -INFINITY;
        #pragma unroll
        for (int i = 0; i < 8; ++i)
            m = fmaxf(m, lrelu(acc[i][j] * gsc + bto));
        red[ty][col] = m;
    }
    __syncthreads();
    {
        int col = threadIdx.x;
        float m = -INFINITY;
        #pragma unroll
        for (int t = 0; t < 16; ++t) m = fmaxf(m, red[t][col]);
        atomicMax(&h5key[b * 1024 + o0 + col], f2key(m));
    }
}

// ---------------- fused FC head: fc1 -> fc2 -> fc3, one block per batch ---
__global__ __launch_bounds__(256) void fchead_kernel(
    const unsigned* __restrict__ h5key,
    const float* __restrict__ fw1, const float* __restrict__ fg1,
    const float* __restrict__ fbt1,
    const float* __restrict__ fw2, const float* __restrict__ fb2,
    const float* __restrict__ fg2, const float* __restrict__ fbt2,
    const float* __restrict__ fw3, const float* __restrict__ fb3,
    float* __restrict__ out) {
    __shared__ float h5[1024];
    __shared__ float f1s[512];
    __shared__ float f2s[256];
    int b = blockIdx.x;
    int tid = threadIdx.x;
    for (int i = tid; i < 1024; i += 256) h5[i] = key2f(h5key[b * 1024 + i]);
    __syncthreads();
    for (int o = tid; o < 512; o += 256) {
        float s = 0.f;
        for (int c = 0; c < 1024; ++c) s += h5[c] * fw1[o * 1024 + c];
        float h = s * (fg1[o] / sqrtf(1.f + 1e-5f)) + fbt1[o];
        f1s[o] = lrelu(h);
    }
    __syncthreads();
    {
        int o = tid;
        float s = fb2[o];
        for (int c = 0; c < 512; ++c) s += f1s[c] * fw2[o * 512 + c];
        float h = s * (fg2[o] / sqrtf(1.f + 1e-5f)) + fbt2[o];
        f2s[o] = lrelu(h);
    }
    __syncthreads();
    if (tid < 3) {
        int o = tid;
        float s = fb3[o];
        for (int c = 0; c < 256; ++c) s += f2s[c] * fw3[o * 256 + c];
        out[b * 3 + o] = s;
    }
}

extern "C" void kernel_launch(void* const* d_in, const int* in_sizes, int n_in,
                              void* d_out, int out_size, void* d_ws, size_t ws_size,
                              hipStream_t stream) {
    const float* points = (const float*)d_in[0];
    const float* w1 = (const float*)d_in[2];
    const float* g1 = (const float*)d_in[3];
    const float* b1 = (const float*)d_in[4];
    const float* w2 = (const float*)d_in[5];
    const float* g2 = (const float*)d_in[6];
    const float* b2 = (const float*)d_in[7];
    const float* w3 = (const float*)d_in[8];
    const float* g3 = (const float*)d_in[9];
    const float* b3 = (const float*)d_in[10];
    const float* w4 = (const float*)d_in[11];
    const float* g4 = (const float*)d_in[12];
    const float* b4 = (const float*)d_in[13];
    const float* w5 = (const float*)d_in[14];
    const float* g5 = (const float*)d_in[15];
    const float* b5 = (const float*)d_in[16];
    const float* fw1 = (const float*)d_in[17];
    const float* fg1 = (const float*)d_in[18];
    const float* fbt1 = (const float*)d_in[19];
    const float* fw2 = (const float*)d_in[20];
    const float* fb2 = (const float*)d_in[21];
    const float* fg2 = (const float*)d_in[22];
    const float* fbt2 = (const float*)d_in[23];
    const float* fw3 = (const float*)d_in[24];
    const float* fb3 = (const float*)d_in[25];

    float* ws = (float*)d_ws;
    float* cat = ws;                                     // 4*4096*512
    float* sq = cat + (long)BATCH * N_PTS * 512;         // 16384
    unsigned* h5key = (unsigned*)(sq + BATCH * N_PTS);   // 4096
    float* f1 = (float*)(h5key + BATCH * 1024);          // 2048 (legacy)
    float* f2 = f1 + BATCH * 512;                        // 1024 (legacy)
    int* idxbuf = (int*)(f2 + BATCH * 256);              // 4*4096*10
    float* dist = (float*)(idxbuf + (long)BATCH * N_PTS * KNN);
    float* uv = dist;   // alias: dist scratch is free once topk is done
    float* maxbuf = dist + (size_t)BATCH * N_PTS * N_PTS;  // 4*4096*32

    // full-matrix symmetric path needs dist + maxbuf scratch
    size_t need = (size_t)((char*)(maxbuf + (size_t)BATCH * N_PTS * 32) -
                           (char*)d_ws);
    bool fullp = ws_size >= need;

    auto knn = [&](const float* xbase, int xstr, int D) {
        sq_kernel<<<64, 256, 0, stream>>>(xbase, xstr, D, sq);
        if (fullp) {
            distsym_kernel<<<dim3(528, 1, BATCH), 256, 0, stream>>>(
                xbase, sq, dist, maxbuf, xstr, D);
            topkms_kernel<<<dim3(N_PTS / 4, BATCH), 256, 0, stream>>>(dist, maxbuf,
                                                                      idxbuf);
        } else {
            for (int r0 = 0; r0 < N_PTS; r0 += 1024) {
                dist_kernel<<<dim3(32, 8, BATCH), 256, 0, stream>>>(xbase, sq, dist,
                                                                    xstr, D, r0);
                topk_kernel<<<dim3(256, BATCH), 256, 0, stream>>>(dist, idxbuf, r0);
            }
        }
    };

    // layer 1: points(3) -> o1 (64) at cat+0 — dist computed on the fly
    sq_kernel<<<64, 256, 0, stream>>>(points, 3, 3, sq);
    knn3_kernel<<<dim3(N_PTS / 4, BATCH), 256, 0, stream>>>(points, sq, idxbuf);
    edgeconv_kernel<3, 64, 16, 16><<<N_PTS * BATCH / 16, 256, 0, stream>>>(
        points, 3, idxbuf, w1, g1, b1, cat, 0);

    // layer 2: o1(64) -> o2 (64) at cat+64
    knn(cat + 0, 512, 64);
    uvgemm_kernel<64, 64><<<dim3(1, 128), 256, 0, stream>>>(cat, 0, w2, uv);
    edgemax_kernel<64><<<1024, 256, 0, stream>>>(uv, idxbuf, g2, b2, cat, 64);

    // layer 3: o2(64) -> o3 (128) at cat+128
    knn(cat + 64, 512, 64);
    uvgemm_kernel<64, 128><<<dim3(2, 128), 256, 0, stream>>>(cat, 64, w3, uv);
    edgemax_kernel<128><<<2048, 256, 0, stream>>>(uv, idxbuf, g3, b3, cat, 128);

    // layer 4: o3(128) -> o4 (256) at cat+256
    knn(cat + 128, 512, 128);
    uvgemm_kernel<128, 256><<<dim3(4, 128), 256, 0, stream>>>(cat, 128, w4, uv);
    edgemax_kernel<256><<<4096, 256, 0, stream>>>(uv, idxbuf, g4, b4, cat, 256);

    // global feature
    init_h5_kernel<<<16, 256, 0, stream>>>(h5key);
    w5max_kernel<<<dim3(4, 32, BATCH), 256, 0, stream>>>(cat, w5, g5, b5, h5key);

    // fused FC head
    fchead_kernel<<<BATCH, 256, 0, stream>>>(h5key, fw1, fg1, fbt1, fw2, fb2,
                                             fg2, fbt2, fw3, fb3, (float*)d_out);
}

// Round 13
// 1651.803 us; speedup vs baseline: 1.2201x; 1.2201x over previous
//
#include <hip/hip_runtime.h>
#include <math.h>

#define N_PTS 4096
#define BATCH 4
#define KNN 10

__device__ __forceinline__ unsigned f2key(float x) {
    unsigned u = __float_as_uint(x);
    return (u & 0x80000000u) ? ~u : (u | 0x80000000u);
}
__device__ __forceinline__ float key2f(unsigned k) {
    unsigned u = (k & 0x80000000u) ? (k & 0x7FFFFFFFu) : ~k;
    return __uint_as_float(u);
}

__device__ __forceinline__ float lrelu(float h) { return (h > 0.f) ? h : 0.2f * h; }

// packed sort key: larger == better; ties on value -> smaller index wins
__device__ __forceinline__ unsigned long long pack_kd(float v, int c) {
    return ((unsigned long long)f2key(v) << 32) | (unsigned)~(unsigned)c;
}

// broadcast 64-bit value from a wave-uniform source lane via readlane
__device__ __forceinline__ unsigned long long bcast64(unsigned long long x, int src) {
    unsigned lo = (unsigned)__builtin_amdgcn_readlane((int)(unsigned)(x & 0xFFFFFFFFu), src);
    unsigned hi = (unsigned)__builtin_amdgcn_readlane((int)(unsigned)(x >> 32), src);
    return ((unsigned long long)hi << 32) | lo;
}

// ---------------- squared norms ----------------
__global__ void sq_kernel(const float* __restrict__ x, int xstr, int D,
                          float* __restrict__ sq) {
    int g = blockIdx.x * blockDim.x + threadIdx.x;
    if (g >= BATCH * N_PTS) return;
    const float* row = x + (long)g * xstr;
    float s = 0.f;
    if ((D & 3) == 0) {
        for (int c = 0; c < D; c += 4) {
            float4 v = *(const float4*)&row[c];
            s += v.x * v.x + v.y * v.y + v.z * v.z + v.w * v.w;
        }
    } else {
        for (int c = 0; c < D; ++c) { float v = row[c]; s += v * v; }
    }
    sq[g] = s;
}

// ---------------- layer-1 knn (D=3): on-the-fly dist + wave top-11 --------
__global__ __launch_bounds__(256) void knn3_kernel(const float* __restrict__ x,
                                                   const float* __restrict__ sq,
                                                   int* __restrict__ idxout) {
    int b = blockIdx.y;
    int wave = threadIdx.x >> 6;
    int lane = threadIdx.x & 63;
    int row = blockIdx.x * 4 + wave;
    const float* xb = x + (long)b * N_PTS * 3;
    const float* sqb = sq + b * N_PTS;
    float x0 = xb[row * 3 + 0], x1 = xb[row * 3 + 1], x2 = xb[row * 3 + 2];
    float sr = sqb[row];

    unsigned long long elem = 0ull, T = 0ull;
    float Tf = -INFINITY;

    int c = lane;
    float y0 = xb[c * 3 + 0], y1 = xb[c * 3 + 1], y2 = xb[c * 3 + 2];
    float sc = sqb[c];
    for (int it = 0; it < 64; ++it) {
        float ny0, ny1, ny2, nsc;
        int nc = c + 64;
        if (it < 63) {
            ny0 = xb[nc * 3 + 0]; ny1 = xb[nc * 3 + 1]; ny2 = xb[nc * 3 + 2];
            nsc = sqb[nc];
        }
        float s = 0.f;
        s += x0 * y0; s += x1 * y1; s += x2 * y2;
        float d = 2.f * s - sr - sc;
        if (__ballot(d >= Tf)) {
            unsigned long long kq = pack_kd(d, c);
            unsigned long long mask;
            while ((mask = __ballot(kq > T)) != 0ull) {
                int src = __ffsll(mask) - 1;
                unsigned long long kb = bcast64(kq, src);
                if (lane == src) kq = 0ull;
                unsigned long long below = __ballot(elem > kb);
                int pos = __popcll(below);
                unsigned long long prev = __shfl_up(elem, 1);
                if (lane == pos) elem = kb;
                else if (lane > pos && lane <= 10) elem = prev;
                T = bcast64(elem, 10);
                Tf = key2f((unsigned)(T >> 32));
            }
        }
        y0 = ny0; y1 = ny1; y2 = ny2; sc = nsc; c = nc;
    }
    if (lane >= 1 && lane <= 10) {
        idxout[((long)b * N_PTS + row) * KNN + (lane - 1)] =
            (int)~(unsigned)(elem & 0xFFFFFFFFull);
    }
}

// ---------------- neg-distance tile GEMM (slab fallback, round-1 exact) ----
__global__ __launch_bounds__(256) void dist_kernel(const float* __restrict__ x,
                                                   const float* __restrict__ sq,
                                                   float* __restrict__ dist,
                                                   int xstr, int D, int row0) {
    __shared__ float As[16][132];
    __shared__ float Bs[16][132];
    int b = blockIdx.z;
    const float* xb = x + (long)b * N_PTS * xstr;
    const float* sqb = sq + b * N_PTS;
    float* db = dist + (long)b * 1024 * N_PTS;
    int r0 = row0 + blockIdx.y * 128;
    int c0 = blockIdx.x * 128;
    int tx = threadIdx.x & 15, ty = threadIdx.x >> 4;
    float acc[8][8] = {};
    int nk = (D + 15) >> 4;
    for (int kt = 0; kt < nk; ++kt) {
        int k0 = kt * 16;
        for (int e = threadIdx.x; e < 2048; e += 256) {
            int kk = e & 15, r = e >> 4;
            int c = k0 + kk;
            As[kk][r] = (c < D) ? xb[(long)(r0 + r) * xstr + c] : 0.f;
            Bs[kk][r] = (c < D) ? xb[(long)(c0 + r) * xstr + c] : 0.f;
        }
        __syncthreads();
        #pragma unroll
        for (int kk = 0; kk < 16; ++kk) {
            float a[8], bb[8];
            *(float4*)&a[0] = *(float4*)&As[kk][ty * 8];
            *(float4*)&a[4] = *(float4*)&As[kk][ty * 8 + 4];
            *(float4*)&bb[0] = *(float4*)&Bs[kk][tx * 8];
            *(float4*)&bb[4] = *(float4*)&Bs[kk][tx * 8 + 4];
            #pragma unroll
            for (int i = 0; i < 8; ++i)
                #pragma unroll
                for (int j = 0; j < 8; ++j) acc[i][j] += a[i] * bb[j];
        }
        __syncthreads();
    }
    #pragma unroll
    for (int i = 0; i < 8; ++i) {
        int lr = blockIdx.y * 128 + ty * 8 + i;
        float sr = sqb[r0 + ty * 8 + i];
        int cb = c0 + tx * 8;
        float4 v0, v1;
        v0.x = 2.f * acc[i][0] - sr - sqb[cb + 0];
        v0.y = 2.f * acc[i][1] - sr - sqb[cb + 1];
        v0.z = 2.f * acc[i][2] - sr - sqb[cb + 2];
        v0.w = 2.f * acc[i][3] - sr - sqb[cb + 3];
        v1.x = 2.f * acc[i][4] - sr - sqb[cb + 4];
        v1.y = 2.f * acc[i][5] - sr - sqb[cb + 5];
        v1.z = 2.f * acc[i][6] - sr - sqb[cb + 6];
        v1.w = 2.f * acc[i][7] - sr - sqb[cb + 7];
        *(float4*)&db[(long)lr * N_PTS + cb] = v0;
        *(float4*)&db[(long)lr * N_PTS + cb + 4] = v1;
    }
}

// ---------------- symmetric full-matrix dist + per-tile row maxima --------
__global__ __launch_bounds__(256) void distsym_kernel(const float* __restrict__ x,
                                                      const float* __restrict__ sq,
                                                      float* __restrict__ dist,
                                                      float* __restrict__ maxbuf,
                                                      int xstr, int D) {
    __shared__ float As[16][132];
    __shared__ float Bs[16][132];
    __shared__ float Tt[64][132];
    int b = blockIdx.z;
    int t = blockIdx.x, br = 0;
    while (t >= 32 - br) { t -= 32 - br; ++br; }
    int bc = br + t;
    const float* xb = x + (long)b * N_PTS * xstr;
    const float* sqb = sq + b * N_PTS;
    float* db = dist + (long)b * N_PTS * N_PTS;
    int r0 = br * 128, c0 = bc * 128;
    int tx = threadIdx.x & 15, ty = threadIdx.x >> 4;
    float acc[8][8] = {};
    int nk = (D + 15) >> 4;
    for (int kt = 0; kt < nk; ++kt) {
        int k0 = kt * 16;
        for (int e = threadIdx.x; e < 2048; e += 256) {
            int kk = e & 15, r = e >> 4;
            int c = k0 + kk;
            As[kk][r] = (c < D) ? xb[(long)(r0 + r) * xstr + c] : 0.f;
            Bs[kk][r] = (c < D) ? xb[(long)(c0 + r) * xstr + c] : 0.f;
        }
        __syncthreads();
        #pragma unroll
        for (int kk = 0; kk < 16; ++kk) {
            float a[8], bb[8];
            *(float4*)&a[0] = *(float4*)&As[kk][ty * 8];
            *(float4*)&a[4] = *(float4*)&As[kk][ty * 8 + 4];
            *(float4*)&bb[0] = *(float4*)&Bs[kk][tx * 8];
            *(float4*)&bb[4] = *(float4*)&Bs[kk][tx * 8 + 4];
            #pragma unroll
            for (int i = 0; i < 8; ++i)
                #pragma unroll
                for (int j = 0; j < 8; ++j) acc[i][j] += a[i] * bb[j];
        }
        __syncthreads();
    }
    float sqr[8], sqc[8];
    #pragma unroll
    for (int i = 0; i < 8; ++i) sqr[i] = sqb[r0 + ty * 8 + i];
    #pragma unroll
    for (int j = 0; j < 8; ++j) sqc[j] = sqb[c0 + tx * 8 + j];
    #pragma unroll
    for (int i = 0; i < 8; ++i) {
        int R = r0 + ty * 8 + i;
        int cb = c0 + tx * 8;
        float4 v0, v1;
        v0.x = 2.f * acc[i][0] - sqr[i] - sqc[0];
        v0.y = 2.f * acc[i][1] - sqr[i] - sqc[1];
        v0.z = 2.f * acc[i][2] - sqr[i] - sqc[2];
        v0.w = 2.f * acc[i][3] - sqr[i] - sqc[3];
        v1.x = 2.f * acc[i][4] - sqr[i] - sqc[4];
        v1.y = 2.f * acc[i][5] - sqr[i] - sqc[5];
        v1.z = 2.f * acc[i][6] - sqr[i] - sqc[6];
        v1.w = 2.f * acc[i][7] - sqr[i] - sqc[7];
        *(float4*)&db[(long)R * N_PTS + cb] = v0;
        *(float4*)&db[(long)R * N_PTS + cb + 4] = v1;
        // row max over this tile (16 tx lanes are consecutive in the wave)
        float tm = fmaxf(fmaxf(fmaxf(v0.x, v0.y), fmaxf(v0.z, v0.w)),
                         fmaxf(fmaxf(v1.x, v1.y), fmaxf(v1.z, v1.w)));
        #pragma unroll
        for (int off = 1; off < 16; off <<= 1)
            tm = fmaxf(tm, __shfl_xor(tm, off, 16));
        if (tx == 0) maxbuf[((long)b * N_PTS + R) * 32 + bc] = tm;
    }
    if (br == bc) return;
    #pragma unroll
    for (int h = 0; h < 2; ++h) {
        __syncthreads();
        if ((tx >> 3) == h) {
            int txl = tx & 7;
            #pragma unroll
            for (int j = 0; j < 8; ++j)
                #pragma unroll
                for (int i = 0; i < 8; ++i)
                    Tt[txl * 8 + j][ty * 8 + i] =
                        (2.f * acc[i][j] - sqc[j]) - sqr[i];
        }
        __syncthreads();
        for (int e = threadIdx.x; e < 2048; e += 256) {
            int rr = e >> 5, cc = (e & 31) << 2;
            *(float4*)&db[(long)(c0 + h * 64 + rr) * N_PTS + r0 + cc] =
                *(const float4*)&Tt[rr][cc];
        }
        // mirrored row maxima from Tt — float4-vectorized (8 b128 reads/thread)
        {
            int rr = threadIdx.x >> 2, q = threadIdx.x & 3;
            float tm = -INFINITY;
            #pragma unroll
            for (int cc = 0; cc < 8; ++cc) {
                float4 v = *(const float4*)&Tt[rr][q * 32 + cc * 4];
                tm = fmaxf(tm, fmaxf(fmaxf(v.x, v.y), fmaxf(v.z, v.w)));
            }
            tm = fmaxf(tm, __shfl_xor(tm, 1, 4));
            tm = fmaxf(tm, __shfl_xor(tm, 2, 4));
            if (q == 0)
                maxbuf[((long)b * N_PTS + c0 + h * 64 + rr) * 32 + br] = tm;
        }
    }
}

// ---------------- wave-collective top-(k+1) (slab fallback) ------
__global__ __launch_bounds__(256) void topk_kernel(const float* __restrict__ dist,
                                                   int* __restrict__ idxout, int row0) {
    int b = blockIdx.y;
    int wave = threadIdx.x >> 6;
    int lane = threadIdx.x & 63;
    int row_local = blockIdx.x * 4 + wave;
    const float4* d4 =
        (const float4*)(dist + (long)b * 1024 * N_PTS + (long)row_local * N_PTS);

    unsigned long long elem = 0ull;
    unsigned long long T = 0ull;
    float Tf = -INFINITY;

    float4 cur = d4[lane];
    for (int jj = 0; jj < 16; ++jj) {
        float4 nxt;
        if (jj < 15) nxt = d4[(jj + 1) * 64 + lane];
        float vmax = fmaxf(fmaxf(cur.x, cur.y), fmaxf(cur.z, cur.w));
        if (__ballot(vmax >= Tf)) {
            int cbase = jj * 256 + lane * 4;
            unsigned long long kc[4];
            kc[0] = pack_kd(cur.x, cbase + 0);
            kc[1] = pack_kd(cur.y, cbase + 1);
            kc[2] = pack_kd(cur.z, cbase + 2);
            kc[3] = pack_kd(cur.w, cbase + 3);
            #pragma unroll
            for (int q = 0; q < 4; ++q) {
                unsigned long long kq = kc[q];
                unsigned long long mask;
                while ((mask = __ballot(kq > T)) != 0ull) {
                    int src = __ffsll(mask) - 1;
                    unsigned long long kb = bcast64(kq, src);
                    if (lane == src) kq = 0ull;
                    unsigned long long below = __ballot(elem > kb);
                    int pos = __popcll(below);
                    unsigned long long prev = __shfl_up(elem, 1);
                    if (lane == pos) elem = kb;
                    else if (lane > pos && lane <= 10) elem = prev;
                    T = bcast64(elem, 10);
                    Tf = key2f((unsigned)(T >> 32));
                }
            }
        }
        cur = nxt;
    }
    if (lane >= 1 && lane <= 10) {
        int c = (int)~(unsigned)(elem & 0xFFFFFFFFu);
        idxout[((long)b * N_PTS + row0 + row_local) * KNN + (lane - 1)] = c;
    }
}

// ---------------- max-skip topk: process tiles in descending-max order ----
__global__ __launch_bounds__(256) void topkms_kernel(const float* __restrict__ dist,
                                                     const float* __restrict__ maxbuf,
                                                     int* __restrict__ idxout) {
    int b = blockIdx.y;
    int wave = threadIdx.x >> 6;
    int lane = threadIdx.x & 63;
    int row = blockIdx.x * 4 + wave;
    const float* drow = dist + (long)b * N_PTS * N_PTS + (long)row * N_PTS;
    float mx = (lane < 32) ? maxbuf[((long)b * N_PTS + row) * 32 + lane] : -INFINITY;

    unsigned long long elem = 0ull, T = 0ull;
    float Tf = -INFINITY;

    while (1) {
        // wave argmax over remaining tile maxima
        float bv = mx; int bi = lane;
        #pragma unroll
        for (int off = 32; off > 0; off >>= 1) {
            float ov = __shfl_xor(bv, off);
            int oi = __shfl_xor(bi, off);
            if (ov > bv || (ov == bv && oi < bi)) { bv = ov; bi = oi; }
        }
        if (!(bv >= Tf)) break;  // all remaining tiles lose to rank-10
        // process tile bi: 128 cols, 2 per lane
        int cb = bi * 128 + lane * 2;
        float2 v = *(const float2*)&drow[cb];
        unsigned long long kc[2];
        kc[0] = pack_kd(v.x, cb);
        kc[1] = pack_kd(v.y, cb + 1);
        #pragma unroll
        for (int q = 0; q < 2; ++q) {
            unsigned long long kq = kc[q];
            unsigned long long mask;
            while ((mask = __ballot(kq > T)) != 0ull) {
                int src = __ffsll(mask) - 1;
                unsigned long long kb = bcast64(kq, src);
                if (lane == src) kq = 0ull;
                unsigned long long below = __ballot(elem > kb);
                int pos = __popcll(below);
                unsigned long long prev = __shfl_up(elem, 1);
                if (lane == pos) elem = kb;
                else if (lane > pos && lane <= 10) elem = prev;
                T = bcast64(elem, 10);
                Tf = key2f((unsigned)(T >> 32));
            }
        }
        if (lane == bi) mx = -INFINITY;  // mark processed
    }
    if (lane >= 1 && lane <= 10) {
        int c = (int)~(unsigned)(elem & 0xFFFFFFFFu);
        idxout[((long)b * N_PTS + row) * KNN + (lane - 1)] = c;
    }
}

// ---------------- edge conv L1 (DIN=3, fused path) ----------------
template <int DIN, int DOUT, int PTS, int TPP>
__global__ __launch_bounds__(256) void edgeconv_kernel(
    const float* __restrict__ x, int xstr, const int* __restrict__ idx,
    const float* __restrict__ w, const float* __restrict__ gamma,
    const float* __restrict__ beta, float* __restrict__ out, int outoff) {
    constexpr int DP = DIN + 1;
    constexpr int C2 = 2 * DIN;
    __shared__ float ctr[PTS][DP];
    __shared__ float nm[PTS][KNN][DP];
    int p0 = blockIdx.x * PTS;
    for (int e = threadIdx.x; e < PTS * DIN; e += 256) {
        int p = e / DIN, c = e - p * DIN;
        ctr[p][c] = x[(long)(p0 + p) * xstr + c];
    }
    __syncthreads();
    for (int e = threadIdx.x; e < PTS * KNN * DIN; e += 256) {
        int p = e / (KNN * DIN);
        int rem = e - p * (KNN * DIN);
        int kk = rem / DIN, c = rem - kk * DIN;
        int g = p0 + p;
        int nb = (g & ~(N_PTS - 1)) + idx[(long)g * KNN + kk];
        nm[p][kk][c] = x[(long)nb * xstr + c] - ctr[p][c];
    }
    __syncthreads();
    int p = threadIdx.x / TPP;
    int og = (threadIdx.x % TPP) * 4;
    float gs[4], bt[4];
    #pragma unroll
    for (int j = 0; j < 4; ++j) {
        gs[j] = gamma[og + j] / sqrtf(1.f + 1e-5f);
        bt[j] = beta[og + j];
    }
    float base[4] = {0.f, 0.f, 0.f, 0.f};
    for (int c = 0; c < DIN; ++c) {
        float cv = ctr[p][c];
        #pragma unroll
        for (int j = 0; j < 4; ++j) base[j] += cv * w[(og + j) * C2 + DIN + c];
    }
    float acc[KNN][4];
    #pragma unroll
    for (int kk = 0; kk < KNN; ++kk)
        #pragma unroll
        for (int j = 0; j < 4; ++j) acc[kk][j] = base[j];
    for (int c = 0; c < DIN; ++c) {
        float w4[4];
        #pragma unroll
        for (int j = 0; j < 4; ++j) w4[j] = w[(og + j) * C2 + c];
        #pragma unroll
        for (int kk = 0; kk < KNN; ++kk) {
            float nv = nm[p][kk][c];
            #pragma unroll
            for (int j = 0; j < 4; ++j) acc[kk][j] += nv * w4[j];
        }
    }
    float best[4] = {-INFINITY, -INFINITY, -INFINITY, -INFINITY};
    #pragma unroll
    for (int kk = 0; kk < KNN; ++kk)
        #pragma unroll
        for (int j = 0; j < 4; ++j)
            best[j] = fmaxf(best[j], lrelu(acc[kk][j] * gs[j] + bt[j]));
    #pragma unroll
    for (int j = 0; j < 4; ++j)
        out[(long)(p0 + p) * 512 + outoff + og + j] = best[j];
}

// ---------------- uv GEMM: uv[r][j] = sum_k x[r][k] * Bcat[k][j] ----------
template <int DIN, int DOUT>
__global__ __launch_bounds__(256) void uvgemm_kernel(
    const float* __restrict__ x, int xoff, const float* __restrict__ w,
    float* __restrict__ uv) {
    constexpr int NC = 2 * DOUT;
    __shared__ float As[16][132];
    __shared__ float Bs[16][132];
    int r0 = blockIdx.y * 128;
    int c0 = blockIdx.x * 128;
    int tx = threadIdx.x & 15, ty = threadIdx.x >> 4;
    float acc[8][8] = {};
    #pragma unroll 1
    for (int kt = 0; kt < DIN / 16; ++kt) {
        int k0 = kt * 16;
        for (int e = threadIdx.x; e < 2048; e += 256) {
            int kk = e & 15, r = e >> 4;
            As[kk][r] = x[(long)(r0 + r) * 512 + xoff + k0 + kk];
            int jg = c0 + r;
            Bs[kk][r] = (jg < DOUT) ? w[(long)jg * (2 * DIN) + k0 + kk]
                                    : w[(long)(jg - DOUT) * (2 * DIN) + DIN + k0 + kk];
        }
        __syncthreads();
        #pragma unroll
        for (int kk = 0; kk < 16; ++kk) {
            float a[8], bb[8];
            *(float4*)&a[0] = *(float4*)&As[kk][ty * 8];
            *(float4*)&a[4] = *(float4*)&As[kk][ty * 8 + 4];
            *(float4*)&bb[0] = *(float4*)&Bs[kk][tx * 8];
            *(float4*)&bb[4] = *(float4*)&Bs[kk][tx * 8 + 4];
            #pragma unroll
            for (int i = 0; i < 8; ++i)
                #pragma unroll
                for (int j = 0; j < 8; ++j) acc[i][j] += a[i] * bb[j];
        }
        __syncthreads();
    }
    #pragma unroll
    for (int i = 0; i < 8; ++i) {
        int r = r0 + ty * 8 + i;
        int cb = c0 + tx * 8;
        *(float4*)&uv[(long)r * NC + cb] = *(float4*)&acc[i][0];
        *(float4*)&uv[(long)r * NC + cb + 4] = *(float4*)&acc[i][4];
    }
}

// ---------------- edge max epilogue: h = u[nb] - u[n] + v[n] --------------
template <int DOUT>
__global__ __launch_bounds__(256) void edgemax_kernel(
    const float* __restrict__ uv, const int* __restrict__ idx,
    const float* __restrict__ gamma, const float* __restrict__ beta,
    float* __restrict__ out, int outoff) {
    constexpr int NC = 2 * DOUT;
    constexpr int TPP = DOUT / 4;
    constexpr int TP = 256 / TPP;
    __shared__ int sidx[TP][KNN];
    int p0 = blockIdx.x * TP;
    for (int e = threadIdx.x; e < TP * KNN; e += 256)
        sidx[e / KNN][e % KNN] = idx[(long)(p0 + e / KNN) * KNN + (e % KNN)];
    __syncthreads();
    int p = threadIdx.x / TPP;
    int og = (threadIdx.x % TPP) * 4;
    int g = p0 + p;
    int base_pt = g & ~(N_PTS - 1);
    const float* rowg = uv + (long)g * NC;
    float4 u_n = *(const float4*)&rowg[og];
    float4 v_n = *(const float4*)&rowg[DOUT + og];
    float c0 = v_n.x - u_n.x, c1 = v_n.y - u_n.y;
    float c2 = v_n.z - u_n.z, c3 = v_n.w - u_n.w;
    const float rs = 1.f / sqrtf(1.f + 1e-5f);
    float gs0 = gamma[og + 0] * rs, gs1 = gamma[og + 1] * rs;
    float gs2 = gamma[og + 2] * rs, gs3 = gamma[og + 3] * rs;
    float bt0 = beta[og + 0], bt1 = beta[og + 1];
    float bt2 = beta[og + 2], bt3 = beta[og + 3];
    float b0 = -INFINITY, b1 = -INFINITY, b2 = -INFINITY, b3 = -INFINITY;
    #pragma unroll
    for (int kk = 0; kk < KNN; ++kk) {
        int nb = base_pt + sidx[p][kk];
        float4 ub = *(const float4*)&uv[(long)nb * NC + og];
        b0 = fmaxf(b0, lrelu((ub.x + c0) * gs0 + bt0));
        b1 = fmaxf(b1, lrelu((ub.y + c1) * gs1 + bt1));
        b2 = fmaxf(b2, lrelu((ub.z + c2) * gs2 + bt2));
        b3 = fmaxf(b3, lrelu((ub.w + c3) * gs3 + bt3));
    }
    float4 o4; o4.x = b0; o4.y = b1; o4.z = b2; o4.w = b3;
    *(float4*)&out[(long)g * 512 + outoff + og] = o4;
}

// ---------------- init h5 key buffer ----------------
__global__ void init_h5_kernel(unsigned* __restrict__ h5key) {
    int t = blockIdx.x * blockDim.x + threadIdx.x;
    if (t < BATCH * 1024) h5key[t] = 0u;
}

// ---------------- w5 GEMM + BN + lrelu + max over n, 128x128 tile ---------
// (proven 120-VGPR configuration; 128x256 variant falsified in round 12 —
//  VGPR 208 -> 1 wave/SIMD -> 470 us. Do not grow this tile.)
__global__ __launch_bounds__(256) void w5max_kernel(
    const float* __restrict__ cat, const float* __restrict__ w5,
    const float* __restrict__ g5, const float* __restrict__ b5,
    unsigned* __restrict__ h5key) {
    __shared__ float As[16][132];
    __shared__ float Bs[16][132];
    int b = blockIdx.z;
    int n0 = blockIdx.y * 128, o0 = blockIdx.x * 128;
    int tx = threadIdx.x & 15, ty = threadIdx.x >> 4;
    const float* A = cat + (long)b * N_PTS * 512;
    float acc[8][8] = {};
    for (int kt = 0; kt < 32; ++kt) {
        int k0 = kt * 16;
        for (int e = threadIdx.x; e < 2048; e += 256) {
            int kk = e & 15, r = e >> 4;
            As[kk][r] = A[(long)(n0 + r) * 512 + k0 + kk];
            Bs[kk][r] = w5[(long)(o0 + r) * 512 + k0 + kk];
        }
        __syncthreads();
        #pragma unroll
        for (int kk = 0; kk < 16; ++kk) {
            float a[8], bb[8];
            *(float4*)&a[0] = *(float4*)&As[kk][ty * 8];
            *(float4*)&a[4] = *(float4*)&As[kk][ty * 8 + 4];
            *(float4*)&bb[0] = *(float4*)&Bs[kk][tx * 8];
            *(float4*)&bb[4] = *(float4*)&Bs[kk][tx * 8 + 4];
            #pragma unroll
            for (int i = 0; i < 8; ++i)
                #pragma unroll
                for (int j = 0; j < 8; ++j) acc[i][j] += a[i] * bb[j];
        }
        __syncthreads();
    }
    float colmax[8];
    #pragma unroll
    for (int j = 0; j < 8; ++j) {
        int o = o0 + tx * 8 + j;
        float gsc = g5[o] / sqrtf(1.f + 1e-5f);
        float bto = b5[o];
        float m = -INFINITY;
        #pragma unroll
        for (int i = 0; i < 8; ++i)
            m = fmaxf(m, lrelu(acc[i][j] * gsc + bto));
        colmax[j] = m;
    }
    __syncthreads();
    float* red = &As[0][0];
    #pragma unroll
    for (int j = 0; j < 8; ++j) red[ty * 128 + tx * 8 + j] = colmax[j];
    __syncthreads();
    if (threadIdx.x < 128) {
        int col = threadIdx.x;
        float m = -INFINITY;
        #pragma unroll
        for (int t = 0; t < 16; ++t) m = fmaxf(m, red[t * 128 + col]);
        atomicMax(&h5key[b * 1024 + o0 + col], f2key(m));
    }
}

// ---------------- fused FC head: fc1 -> fc2 -> fc3, one block per batch ---
__global__ __launch_bounds__(256) void fchead_kernel(
    const unsigned* __restrict__ h5key,
    const float* __restrict__ fw1, const float* __restrict__ fg1,
    const float* __restrict__ fbt1,
    const float* __restrict__ fw2, const float* __restrict__ fb2,
    const float* __restrict__ fg2, const float* __restrict__ fbt2,
    const float* __restrict__ fw3, const float* __restrict__ fb3,
    float* __restrict__ out) {
    __shared__ float h5[1024];
    __shared__ float f1s[512];
    __shared__ float f2s[256];
    int b = blockIdx.x;
    int tid = threadIdx.x;
    for (int i = tid; i < 1024; i += 256) h5[i] = key2f(h5key[b * 1024 + i]);
    __syncthreads();
    for (int o = tid; o < 512; o += 256) {
        float s = 0.f;
        for (int c = 0; c < 1024; ++c) s += h5[c] * fw1[o * 1024 + c];
        float h = s * (fg1[o] / sqrtf(1.f + 1e-5f)) + fbt1[o];
        f1s[o] = lrelu(h);
    }
    __syncthreads();
    {
        int o = tid;
        float s = fb2[o];
        for (int c = 0; c < 512; ++c) s += f1s[c] * fw2[o * 512 + c];
        float h = s * (fg2[o] / sqrtf(1.f + 1e-5f)) + fbt2[o];
        f2s[o] = lrelu(h);
    }
    __syncthreads();
    if (tid < 3) {
        int o = tid;
        float s = fb3[o];
        for (int c = 0; c < 256; ++c) s += f2s[c] * fw3[o * 256 + c];
        out[b * 3 + o] = s;
    }
}

extern "C" void kernel_launch(void* const* d_in, const int* in_sizes, int n_in,
                              void* d_out, int out_size, void* d_ws, size_t ws_size,
                              hipStream_t stream) {
    const float* points = (const float*)d_in[0];
    const float* w1 = (const float*)d_in[2];
    const float* g1 = (const float*)d_in[3];
    const float* b1 = (const float*)d_in[4];
    const float* w2 = (const float*)d_in[5];
    const float* g2 = (const float*)d_in[6];
    const float* b2 = (const float*)d_in[7];
    const float* w3 = (const float*)d_in[8];
    const float* g3 = (const float*)d_in[9];
    const float* b3 = (const float*)d_in[10];
    const float* w4 = (const float*)d_in[11];
    const float* g4 = (const float*)d_in[12];
    const float* b4 = (const float*)d_in[13];
    const float* w5 = (const float*)d_in[14];
    const float* g5 = (const float*)d_in[15];
    const float* b5 = (const float*)d_in[16];
    const float* fw1 = (const float*)d_in[17];
    const float* fg1 = (const float*)d_in[18];
    const float* fbt1 = (const float*)d_in[19];
    const float* fw2 = (const float*)d_in[20];
    const float* fb2 = (const float*)d_in[21];
    const float* fg2 = (const float*)d_in[22];
    const float* fbt2 = (const float*)d_in[23];
    const float* fw3 = (const float*)d_in[24];
    const float* fb3 = (const float*)d_in[25];

    float* ws = (float*)d_ws;
    float* cat = ws;                                     // 4*4096*512
    float* sq = cat + (long)BATCH * N_PTS * 512;         // 16384
    unsigned* h5key = (unsigned*)(sq + BATCH * N_PTS);   // 4096
    float* f1 = (float*)(h5key + BATCH * 1024);          // 2048 (legacy)
    float* f2 = f1 + BATCH * 512;                        // 1024 (legacy)
    int* idxbuf = (int*)(f2 + BATCH * 256);              // 4*4096*10
    float* dist = (float*)(idxbuf + (long)BATCH * N_PTS * KNN);
    float* uv = dist;   // alias: dist scratch is free once topk is done
    float* maxbuf = dist + (size_t)BATCH * N_PTS * N_PTS;  // 4*4096*32

    // full-matrix symmetric path needs dist + maxbuf scratch
    size_t need = (size_t)((char*)(maxbuf + (size_t)BATCH * N_PTS * 32) -
                           (char*)d_ws);
    bool fullp = ws_size >= need;

    auto knn = [&](const float* xbase, int xstr, int D) {
        sq_kernel<<<64, 256, 0, stream>>>(xbase, xstr, D, sq);
        if (fullp) {
            distsym_kernel<<<dim3(528, 1, BATCH), 256, 0, stream>>>(
                xbase, sq, dist, maxbuf, xstr, D);
            topkms_kernel<<<dim3(N_PTS / 4, BATCH), 256, 0, stream>>>(dist, maxbuf,
                                                                      idxbuf);
        } else {
            for (int r0 = 0; r0 < N_PTS; r0 += 1024) {
                dist_kernel<<<dim3(32, 8, BATCH), 256, 0, stream>>>(xbase, sq, dist,
                                                                    xstr, D, r0);
                topk_kernel<<<dim3(256, BATCH), 256, 0, stream>>>(dist, idxbuf, r0);
            }
        }
    };

    // layer 1: points(3) -> o1 (64) at cat+0 — dist computed on the fly
    sq_kernel<<<64, 256, 0, stream>>>(points, 3, 3, sq);
    knn3_kernel<<<dim3(N_PTS / 4, BATCH), 256, 0, stream>>>(points, sq, idxbuf);
    edgeconv_kernel<3, 64, 16, 16><<<N_PTS * BATCH / 16, 256, 0, stream>>>(
        points, 3, idxbuf, w1, g1, b1, cat, 0);

    // layer 2: o1(64) -> o2 (64) at cat+64
    knn(cat + 0, 512, 64);
    uvgemm_kernel<64, 64><<<dim3(1, 128), 256, 0, stream>>>(cat, 0, w2, uv);
    edgemax_kernel<64><<<1024, 256, 0, stream>>>(uv, idxbuf, g2, b2, cat, 64);

    // layer 3: o2(64) -> o3 (128) at cat+128
    knn(cat + 64, 512, 64);
    uvgemm_kernel<64, 128><<<dim3(2, 128), 256, 0, stream>>>(cat, 64, w3, uv);
    edgemax_kernel<128><<<2048, 256, 0, stream>>>(uv, idxbuf, g3, b3, cat, 128);

    // layer 4: o3(128) -> o4 (256) at cat+256
    knn(cat + 128, 512, 128);
    uvgemm_kernel<128, 256><<<dim3(4, 128), 256, 0, stream>>>(cat, 128, w4, uv);
    edgemax_kernel<256><<<4096, 256, 0, stream>>>(uv, idxbuf, g4, b4, cat, 256);

    // global feature
    init_h5_kernel<<<16, 256, 0, stream>>>(h5key);
    w5max_kernel<<<dim3(8, 32, BATCH), 256, 0, stream>>>(cat, w5, g5, b5, h5key);

    // fused FC head
    fchead_kernel<<<BATCH, 256, 0, stream>>>(h5key, fw1, fg1, fbt1, fw2, fb2,
                                             fg2, fbt2, fw3, fb3, (float*)d_out);
}